// Round 7
// baseline (134.545 us; speedup 1.0000x reference)
//
#include <hip/hip_runtime.h>
#include <math.h>

// Problem constants
constexpr int Bn = 32;
constexpr int Cn = 512;
constexpr int Tn = 1024;
constexpr int KS = 13;

// Tiling
constexpr int CB   = 64;           // channels per block
constexpr int TT   = 64;           // timesteps per chunk
constexpr int NCH  = Tn / TT;      // 16 chunks
constexpr int DSTR = TT + 1;       // LDS row stride (odd -> conflict-free)
constexpr int NB   = 2;            // drive-slot ring depth (LDS 43 KB -> 3 blocks/CU)
constexpr int NL   = 34;           // input rows per conv thread (22 + 12 halo)

// 256 blocks (32 b x 8 c-groups) x 320 threads (5 waves).
// r6 structure unchanged except NB 4->2: LDS 75.3 KB -> 43 KB so multiple
// blocks can co-reside on a CU. Theory: r3/r5/r6's unexplained ~7K cyc/chunk
// wall is 2-blocks-per-CU SERIALIZATION (75.3 KB rounds to >half of 160 KB
// LDS), not intra-block stalls. Roles:
//   wave 0    (scan) : LDS only. Consumes D[k%NB], packs spikes to Sb[k].
//   waves 1-3 (conv) : global LOADS + LDS writes only. Ping-pong reg prefetch.
//   wave 4   (store) : LDS reads + global STORES only — never waits vmcnt.
// All fp32 math uses explicit _rn intrinsics (one rounding per numpy op, no
// FMA) — bit-identical to the validated round-2/3/5/6 kernels.

#define SCAN16(DV, TB)                                                   \
  _Pragma("unroll")                                                      \
  for (int j = 0; j < 16; ++j) {                                         \
    const float rthr = (mem > 0.5f) ? 0.5f : 0.0f;  /* reset: OLD mem */ \
    float a_  = __fmul_rn(0.95f, mem);                                   \
    float s2_ = __fadd_rn(a_, DV[j]);                                    \
    mem = __fsub_rn(s2_, rthr);                                          \
    const unsigned int bit = (mem > 0.5f) ? 1u : 0u;                     \
    if ((TB) + j < 32) lo |= bit << ((TB) + j);                          \
    else               hi |= bit << ((TB) + j - 32);                     \
  }

__global__ __launch_bounds__(320, 1)
void snn_fused(const float* __restrict__ x, const float* __restrict__ wp,
               float* __restrict__ out) {
  __shared__ float D[NB][CB][DSTR];          // drive slot ring (33.3 KB)
  __shared__ unsigned long long Sb[NCH][CB]; // spike bitmasks, no reuse (8 KB)
  __shared__ unsigned int prod[NB];          // producer counters per slot
  __shared__ unsigned int scanProg;          // chunks fully scanned

  const int tid = threadIdx.x;
  const int b   = blockIdx.y;
  const int c0  = blockIdx.x * CB;
  const long xbase = (long)b * Cn * Tn;

  if (tid < NB) prod[tid] = 0u;
  if (tid == NB) scanProg = 0u;

  // ---- Gaussian weights, numpy float32 bit-emulation (validated) ----
  float kw[KS];
  {
    float w  = wp[0];
    float wc = fminf(fmaxf(w, 1.0f), 10.0f);      // clip(w, 1, 10)
    float sigma = __fadd_rn(5.5f, wc);
    float e[KS];
#pragma unroll
    for (int i = 0; i < KS; ++i) {
      float q = __fdiv_rn((float)(i - 6), sigma);
      float t = __fmul_rn(-0.5f, __fmul_rn(q, q));
      e[i] = (float)exp((double)t);
    }
    // numpy pairwise_sum order for n=13
    float s = __fadd_rn(
        __fadd_rn(__fadd_rn(e[0], e[1]), __fadd_rn(e[2], e[3])),
        __fadd_rn(__fadd_rn(e[4], e[5]), __fadd_rn(e[6], e[7])));
    s = __fadd_rn(s, e[8]);  s = __fadd_rn(s, e[9]);  s = __fadd_rn(s, e[10]);
    s = __fadd_rn(s, e[11]); s = __fadd_rn(s, e[12]);
#pragma unroll
    for (int i = 0; i < KS; ++i) kw[i] = __fdiv_rn(e[i], s);
  }

  __syncthreads();   // once: flags zeroed

  if (tid < 64) {
    // ======================= scan wave (consumer, LDS-only) =============
    const int c = tid;
    float mem = 0.0f;
    for (int k = 0; k < NCH; ++k) {
      const int slot = k & (NB - 1);
      const unsigned need = 3u * ((unsigned)(k / NB) + 1u);
      while (__hip_atomic_load(&prod[slot], __ATOMIC_ACQUIRE,
                               __HIP_MEMORY_SCOPE_WORKGROUP) < need) {}
      const float* Dc = &D[slot][c][0];     // LDS row (2-way alias: free)
      unsigned int lo = 0u, hi = 0u;
      float dvA[16], dvB[16];               // named arrays, const idx only
#pragma unroll
      for (int j = 0; j < 16; ++j) dvA[j] = Dc[j];
#pragma unroll
      for (int j = 0; j < 16; ++j) dvB[j] = Dc[16 + j];   // lookahead g=1
      SCAN16(dvA, 0)
#pragma unroll
      for (int j = 0; j < 16; ++j) dvA[j] = Dc[32 + j];   // lookahead g=2
      SCAN16(dvB, 16)
#pragma unroll
      for (int j = 0; j < 16; ++j) dvB[j] = Dc[48 + j];   // lookahead g=3
      SCAN16(dvA, 32)
      SCAN16(dvB, 48)
      Sb[k][c] = ((unsigned long long)hi << 32) | (unsigned long long)lo;
      if (tid == 0)
        __hip_atomic_fetch_add(&scanProg, 1u, __ATOMIC_RELEASE,
                               __HIP_MEMORY_SCOPE_WORKGROUP);
    }
  } else if (tid < 256) {
    // ============== conv waves (producers, loads + LDS only) ============
    const int ctid = tid - 64;
    const int col  = ctid & 63;               // t-column (lane)
    const int segS = (ctid >> 6) * 21;        // 0, 21, 42 (rows 22 each)
    const int cin0 = c0 + segS - 6;

    float xp[NL], xn[NL];                     // proven scratch-free pair

    auto load_chunk = [&](int m, float* dst) {
#pragma unroll
      for (int j = 0; j < NL; ++j) {
        const int gc = cin0 + j;
        float v = 0.0f;
        if (gc >= 0 && gc < Cn)               // zero pad; wave-uniform branch
          v = x[xbase + (long)gc * Tn + m * TT + col];
        dst[j] = v;
      }
    };
    auto conv_chunk = [&](const float* xs, int p) {
#pragma unroll
      for (int r = 0; r < 22; ++r) {
        float acc = __fmul_rn(kw[0], xs[r]);  // ascending, no FMA
#pragma unroll
        for (int i = 1; i < KS; ++i)
          acc = __fadd_rn(acc, __fmul_rn(kw[i], xs[r + i]));
        D[p][segS + r][col] = __fsub_rn(xs[r + 6], acc);  // x - x_mean
      }
    };

    load_chunk(0, xp);
    for (int k = 0; k < NCH; ++k) {
      if (k + 1 < NCH) load_chunk(k + 1, xn); // issue loads first
      if (k >= NB) {                          // wait for slot to be consumed
        const unsigned need = (unsigned)(k - NB + 1);
        while (__hip_atomic_load(&scanProg, __ATOMIC_ACQUIRE,
                                 __HIP_MEMORY_SCOPE_WORKGROUP) < need) {}
      }
      conv_chunk(xp, k & (NB - 1));
      if (col == 0)
        __hip_atomic_fetch_add(&prod[k & (NB - 1)], 1u, __ATOMIC_RELEASE,
                               __HIP_MEMORY_SCOPE_WORKGROUP);
      if (k + 1 < NCH) {
#pragma unroll
        for (int j = 0; j < NL; ++j) xp[j] = xn[j];
      }
    }
  } else {
    // ====== store wave (LDS reads + global stores, NEVER waits vmcnt) ===
    const int col = tid & 63;                 // t-column (lane)
    for (int k = 0; k < NCH; ++k) {
      while (__hip_atomic_load(&scanProg, __ATOMIC_ACQUIRE,
                               __HIP_MEMORY_SCOPE_WORKGROUP)
             < (unsigned)(k + 1)) {}
      const int t0p = k * TT;
#pragma unroll 8
      for (int r = 0; r < CB; ++r) {
        const unsigned long long wb = Sb[k][r];          // LDS broadcast
        const float v = ((wb >> col) & 1ull) ? 1.0f : 0.0f;
        out[xbase + (long)(c0 + r) * Tn + t0p + col] = v; // fire & forget
      }
    }
  }
}

extern "C" void kernel_launch(void* const* d_in, const int* in_sizes, int n_in,
                              void* d_out, int out_size, void* d_ws, size_t ws_size,
                              hipStream_t stream) {
  const float* x  = (const float*)d_in[0];
  const float* w  = (const float*)d_in[1];
  float* out      = (float*)d_out;
  dim3 grid(Cn / CB, Bn, 1);
  snn_fused<<<grid, 320, 0, stream>>>(x, w, out);
}

// Round 8
// 126.830 us; speedup vs baseline: 1.0608x; 1.0608x over previous
//
#include <hip/hip_runtime.h>
#include <math.h>

// Problem constants
constexpr int Bn = 32;
constexpr int Cn = 512;
constexpr int Tn = 1024;
constexpr int KS = 13;

// Tiling
constexpr int CB   = 64;           // channels per block
constexpr int TT   = 64;           // timesteps per chunk
constexpr int NCH  = Tn / TT;      // 16 chunks
constexpr int DSTR = TT + 1;       // LDS row stride (odd -> conflict-free)
constexpr int NB   = 4;            // drive-slot ring depth
constexpr int NCW  = 4;            // conv waves
constexpr int SEG  = CB / NCW;     // 16 output rows per conv thread
constexpr int NL   = SEG + KS - 1; // 28 input rows per conv thread

// 256 blocks (32 b x 8 c-groups) x 384 threads (6 waves), 1 block/CU.
// r6/r7's ~5000 cyc/chunk stall diagnosis: the conv waves fully drained their
// prefetch queue every chunk via (a) the xp<-xn register copy (vmcnt(0)) and
// (b) the RELEASE fetch_add (legalizer emits vmcnt(0)+lgkmcnt(0) at workgroup
// release). Fixes here:
//   (a) 3-buffer load rotation (xA/xB/xC named arrays, distance-2 prefetch,
//       unroll-by-3 loop, no copies, no pointer PHIs -> no scratch) — the
//       wait before conv k is vmcnt(~56), never 0; queue never drains.
//   (b) producer signal = explicit "s_waitcnt lgkmcnt(0)" + RELAXED ds_add
//       (consumer only needs LDS ordering) — no vmcnt drain.
// Roles: wave 0 scan (LDS only) | waves 1-4 conv (loads + LDS) | wave 5
// store (LDS + fire-and-forget global stores, never waits vmcnt).
// All fp32 math uses explicit _rn intrinsics (one rounding per numpy op, no
// FMA) — bit-identical to the validated round-2..7 kernels.

#define SCAN16(DV, TB)                                                   \
  _Pragma("unroll")                                                      \
  for (int j = 0; j < 16; ++j) {                                         \
    const float rthr = (mem > 0.5f) ? 0.5f : 0.0f;  /* reset: OLD mem */ \
    float a_  = __fmul_rn(0.95f, mem);                                   \
    float s2_ = __fadd_rn(a_, DV[j]);                                    \
    mem = __fsub_rn(s2_, rthr);                                          \
    const unsigned int bit = (mem > 0.5f) ? 1u : 0u;                     \
    if ((TB) + j < 32) lo |= bit << ((TB) + j);                          \
    else               hi |= bit << ((TB) + j - 32);                     \
  }

__global__ __launch_bounds__(384, 1)
void snn_fused(const float* __restrict__ x, const float* __restrict__ wp,
               float* __restrict__ out) {
  __shared__ float D[NB][CB][DSTR];          // drive slot ring (66.6 KB)
  __shared__ unsigned long long Sb[NCH][CB]; // spike bitmasks, no reuse (8 KB)
  __shared__ unsigned int prod[NB];          // producer counters per slot
  __shared__ unsigned int scanProg;          // chunks fully scanned

  const int tid = threadIdx.x;
  const int b   = blockIdx.y;
  const int c0  = blockIdx.x * CB;
  const long xbase = (long)b * Cn * Tn;

  if (tid < NB) prod[tid] = 0u;
  if (tid == NB) scanProg = 0u;

  // ---- Gaussian weights, numpy float32 bit-emulation (validated) ----
  float kw[KS];
  {
    float w  = wp[0];
    float wc = fminf(fmaxf(w, 1.0f), 10.0f);      // clip(w, 1, 10)
    float sigma = __fadd_rn(5.5f, wc);
    float e[KS];
#pragma unroll
    for (int i = 0; i < KS; ++i) {
      float q = __fdiv_rn((float)(i - 6), sigma);
      float t = __fmul_rn(-0.5f, __fmul_rn(q, q));
      e[i] = (float)exp((double)t);
    }
    // numpy pairwise_sum order for n=13
    float s = __fadd_rn(
        __fadd_rn(__fadd_rn(e[0], e[1]), __fadd_rn(e[2], e[3])),
        __fadd_rn(__fadd_rn(e[4], e[5]), __fadd_rn(e[6], e[7])));
    s = __fadd_rn(s, e[8]);  s = __fadd_rn(s, e[9]);  s = __fadd_rn(s, e[10]);
    s = __fadd_rn(s, e[11]); s = __fadd_rn(s, e[12]);
#pragma unroll
    for (int i = 0; i < KS; ++i) kw[i] = __fdiv_rn(e[i], s);
  }

  __syncthreads();   // once: flags zeroed

  if (tid < 64) {
    // ======================= scan wave (consumer, LDS-only) =============
    const int c = tid;
    float mem = 0.0f;
    for (int k = 0; k < NCH; ++k) {
      const int slot = k & (NB - 1);
      const unsigned need = (unsigned)NCW * ((unsigned)(k >> 2) + 1u);
      while (__hip_atomic_load(&prod[slot], __ATOMIC_ACQUIRE,
                               __HIP_MEMORY_SCOPE_WORKGROUP) < need) {}
      const float* Dc = &D[slot][c][0];     // LDS row (2-way alias: free)
      unsigned int lo = 0u, hi = 0u;
      float dvA[16], dvB[16];               // named arrays, const idx only
#pragma unroll
      for (int j = 0; j < 16; ++j) dvA[j] = Dc[j];
#pragma unroll
      for (int j = 0; j < 16; ++j) dvB[j] = Dc[16 + j];   // lookahead g=1
      SCAN16(dvA, 0)
#pragma unroll
      for (int j = 0; j < 16; ++j) dvA[j] = Dc[32 + j];   // lookahead g=2
      SCAN16(dvB, 16)
#pragma unroll
      for (int j = 0; j < 16; ++j) dvB[j] = Dc[48 + j];   // lookahead g=3
      SCAN16(dvA, 32)
      SCAN16(dvB, 48)
      Sb[k][c] = ((unsigned long long)hi << 32) | (unsigned long long)lo;
      if (tid == 0)
        __hip_atomic_fetch_add(&scanProg, 1u, __ATOMIC_RELEASE,
                               __HIP_MEMORY_SCOPE_WORKGROUP);
    }
  } else if (tid < 64 + 64 * NCW) {
    // ============== conv waves (producers, loads + LDS only) ============
    const int ctid = tid - 64;
    const int col  = ctid & 63;               // t-column (lane)
    const int segS = (ctid >> 6) * SEG;       // 0,16,32,48
    const int cin0 = c0 + segS - 6;

    float xA[NL], xB[NL], xC[NL];             // 3-buffer rotation (named)

    auto load_chunk = [&](int m, float* dst) {
#pragma unroll
      for (int j = 0; j < NL; ++j) {
        const int gc = cin0 + j;
        float v = 0.0f;
        if (gc >= 0 && gc < Cn)               // zero pad; per-wave uniform
          v = x[xbase + (long)gc * Tn + m * TT + col];
        dst[j] = v;
      }
    };
    auto conv_chunk = [&](const float* xs, int p) {
#pragma unroll
      for (int r = 0; r < SEG; ++r) {
        float acc = __fmul_rn(kw[0], xs[r]);  // ascending, no FMA
#pragma unroll
        for (int i = 1; i < KS; ++i)
          acc = __fadd_rn(acc, __fmul_rn(kw[i], xs[r + i]));
        D[p][segS + r][col] = __fsub_rn(xs[r + 6], acc);  // x - x_mean
      }
    };

    // STEP(K): issue loads K+2 first (deepen queue), wait slot, conv K,
    // then LDS-ordered relaxed signal (NO vmcnt drain anywhere).
#define STEP(K, BC, BL)                                                  \
    do {                                                                 \
      if ((K) + 2 < NCH) load_chunk((K) + 2, BL);                        \
      if ((K) >= NB) {                                                   \
        const unsigned need_ = (unsigned)((K) - NB + 1);                 \
        while (__hip_atomic_load(&scanProg, __ATOMIC_ACQUIRE,            \
                                 __HIP_MEMORY_SCOPE_WORKGROUP) < need_) {} \
      }                                                                  \
      conv_chunk(BC, (K) & (NB - 1));                                    \
      __asm__ __volatile__("s_waitcnt lgkmcnt(0)" ::: "memory");         \
      if (col == 0)                                                      \
        __hip_atomic_fetch_add(&prod[(K) & (NB - 1)], 1u,                \
                               __ATOMIC_RELAXED,                         \
                               __HIP_MEMORY_SCOPE_WORKGROUP);            \
    } while (0)

    load_chunk(0, xA);
    load_chunk(1, xB);
    for (int kb = 0; kb < NCH - 1; kb += 3) {  // kb = 0,3,6,9,12 -> k=0..14
      STEP(kb + 0, xA, xC);
      STEP(kb + 1, xB, xA);
      STEP(kb + 2, xC, xB);
    }
    STEP(NCH - 1, xA, xC);                     // k=15 (load 17 skipped)
#undef STEP
  } else {
    // ====== store wave (LDS reads + global stores, NEVER waits vmcnt) ===
    const int col = tid & 63;                 // t-column (lane)
    for (int k = 0; k < NCH; ++k) {
      while (__hip_atomic_load(&scanProg, __ATOMIC_ACQUIRE,
                               __HIP_MEMORY_SCOPE_WORKGROUP)
             < (unsigned)(k + 1)) {}
      const int t0p = k * TT;
#pragma unroll 8
      for (int r = 0; r < CB; ++r) {
        const unsigned long long wb = Sb[k][r];          // LDS broadcast
        const float v = ((wb >> col) & 1ull) ? 1.0f : 0.0f;
        out[xbase + (long)(c0 + r) * Tn + t0p + col] = v; // fire & forget
      }
    }
  }
}

extern "C" void kernel_launch(void* const* d_in, const int* in_sizes, int n_in,
                              void* d_out, int out_size, void* d_ws, size_t ws_size,
                              hipStream_t stream) {
  const float* x  = (const float*)d_in[0];
  const float* w  = (const float*)d_in[1];
  float* out      = (float*)d_out;
  dim3 grid(Cn / CB, Bn, 1);
  snn_fused<<<grid, 384, 0, stream>>>(x, w, out);
}